// Round 6
// baseline (222.524 us; speedup 1.0000x reference)
//
#include <hip/hip_runtime.h>

// Problem constants
#define S_TOTAL 19648      // B*N sequential LSTM steps
#define T_CH    12         // chains (MFMA N dim, padded to 16)
#define HID     128
#define NT      256        // 4 waves per block

// R23: TWO CO-RESIDENT BLOCKS PER CU (hardware anti-phase).
// R22 post-mortem: per-step 2834cy = 1351 VALU + 675 MFMA + ~800 latency;
// lockstep waves share phases so pipes serialize, and R18-R21 proved the
// compiler can't anti-phase two chains in one stream. Fix: two
// INDEPENDENT 4-wave blocks per CU (separate s_barriers) -> each SIMD
// carries one wave of each block; the CU scheduler interleaves their
// MFMA/gate phases naturally (m114). Each wave now owns 2 j-tiles
// (32 rows, 40 MFMA/step, A-frags 160 regs); __launch_bounds__(256,2)
// caps 256 regs/wave so 2 blocks x 4 waves = 8 waves/CU co-reside.
// 504 chunks x 39 outputs (chunk=39 validated bit-identical in R18),
// WARMUP=32 -> 71 steps/block vs R22's 109.
// FP order per element, MFMA split chains, gate math, pout tree: all
// byte-identical to R22 -> absmax must stay 0.0004882812.
#define CHUNK_L 39
#define NBLK    504        // ceil(19648/39)
#define WARMUP  32

typedef _Float16 half8  __attribute__((ext_vector_type(8)));
typedef _Float16 half4v __attribute__((ext_vector_type(4)));
typedef _Float16 half2v __attribute__((ext_vector_type(2)));
typedef float f4 __attribute__((ext_vector_type(4)));

#define NLOG2E  (-1.4426950408889634f)   // -log2(e): folded into i,f,o rows
#define N2LOG2E (-2.8853900817779268f)   // -2log2(e): folded into g rows

#if __has_builtin(__builtin_amdgcn_exp2f)
#define EXP2(x) __builtin_amdgcn_exp2f(x)
#else
#define EXP2(x) __expf((x) * 0.69314718055994531f)
#endif

__device__ __forceinline__ float sigz(float z) {   // z pre-scaled by -log2e
    return __builtin_amdgcn_rcpf(1.0f + EXP2(z));
}
__device__ __forceinline__ float tanz(float z) {   // z pre-scaled by -2log2e
    return __builtin_fmaf(2.0f, __builtin_amdgcn_rcpf(1.0f + EXP2(z)), -1.0f);
}
__device__ __forceinline__ float fdot2(half2v a, half2v b, float c) {
    return __builtin_amdgcn_fdot2(a, b, c, false);
}
#define MFMA(A, B, C) __builtin_amdgcn_mfma_f32_16x16x32_f16(A, B, C, 0, 0, 0)

// Bit-identical reduction of the 32 swizzled partials for output row l:
// per tile t: (p0+p1)+(p2+p3) over qk, then sequential fold t=0..7, +blin.
#define RD8(PRV, DST)                                                    \
    {                                                                    \
        const int b4 = (4 * l) & 31;                                     \
        const f4 v0 = *(const f4*)&(PRV)[(b4 +  0) & 31];                \
        const f4 v1 = *(const f4*)&(PRV)[(b4 +  4) & 31];                \
        const f4 v2 = *(const f4*)&(PRV)[(b4 +  8) & 31];                \
        const f4 v3 = *(const f4*)&(PRV)[(b4 + 12) & 31];                \
        const f4 v4 = *(const f4*)&(PRV)[(b4 + 16) & 31];                \
        const f4 v5 = *(const f4*)&(PRV)[(b4 + 20) & 31];                \
        const f4 v6 = *(const f4*)&(PRV)[(b4 + 24) & 31];                \
        const f4 v7 = *(const f4*)&(PRV)[(b4 + 28) & 31];                \
        float acc = (v0.x + v0.y) + (v0.z + v0.w);                       \
        acc += (v1.x + v1.y) + (v1.z + v1.w);                            \
        acc += (v2.x + v2.y) + (v2.z + v2.w);                            \
        acc += (v3.x + v3.y) + (v3.z + v3.w);                            \
        acc += (v4.x + v4.y) + (v4.z + v4.w);                            \
        acc += (v5.x + v5.y) + (v5.z + v5.w);                            \
        acc += (v6.x + v6.y) + (v6.z + v6.w);                            \
        acc += (v7.x + v7.y) + (v7.z + v7.w);                            \
        DST = acc + blin;                                                \
    }

// 20 MFMAs for one j-tile; split chains (depth 3 + 2), R22-exact order.
// Declares the 4 gate accumulators AC0..AC3. Uses B0..B4 from scope.
#define TILE_MFMA(AT, AC0, AC1, AC2, AC3)                                \
    f4 AC0, AC1, AC2, AC3;                                               \
    {                                                                    \
        const f4 z = {0.f, 0.f, 0.f, 0.f};                               \
        f4 a0A = MFMA(AT[0][4], B4, z), a1A = MFMA(AT[1][4], B4, z);     \
        f4 a2A = MFMA(AT[2][4], B4, z), a3A = MFMA(AT[3][4], B4, z);     \
        f4 a0B = MFMA(AT[0][2], B2, z), a1B = MFMA(AT[1][2], B2, z);     \
        f4 a2B = MFMA(AT[2][2], B2, z), a3B = MFMA(AT[3][2], B2, z);     \
        a0A = MFMA(AT[0][0], B0, a0A); a1A = MFMA(AT[1][0], B0, a1A);    \
        a2A = MFMA(AT[2][0], B0, a2A); a3A = MFMA(AT[3][0], B0, a3A);    \
        a0B = MFMA(AT[0][3], B3, a0B); a1B = MFMA(AT[1][3], B3, a1B);    \
        a2B = MFMA(AT[2][3], B3, a2B); a3B = MFMA(AT[3][3], B3, a3B);    \
        a0A = MFMA(AT[0][1], B1, a0A); a1A = MFMA(AT[1][1], B1, a1A);    \
        a2A = MFMA(AT[2][1], B1, a2A); a3A = MFMA(AT[3][1], B1, a3A);    \
        AC0 = a0A + a0B; AC1 = a1A + a1B;                                \
        AC2 = a2A + a2B; AC3 = a3A + a3B;                                \
    }

// Gate math for one tile (R22-exact FP order). Updates C0..C3, fills HV.
#define TILE_GATES(AC0, AC1, AC2, AC3, C0, C1, C2, C3, HV)               \
    {                                                                    \
        const float i0 = sigz(AC0[0]), f0 = sigz(AC1[0]);                \
        const float g0 = tanz(AC2[0]), o0 = sigz(AC3[0]);                \
        C0 = __builtin_fmaf(f0, C0, i0 * g0);                            \
        const float h0 = o0 * tanz(C0 * N2LOG2E);                        \
        const float i1 = sigz(AC0[1]), f1 = sigz(AC1[1]);                \
        const float g1 = tanz(AC2[1]), o1 = sigz(AC3[1]);                \
        C1 = __builtin_fmaf(f1, C1, i1 * g1);                            \
        const float h1 = o1 * tanz(C1 * N2LOG2E);                        \
        const float i2 = sigz(AC0[2]), f2 = sigz(AC1[2]);                \
        const float g2 = tanz(AC2[2]), o2 = sigz(AC3[2]);                \
        C2 = __builtin_fmaf(f2, C2, i2 * g2);                            \
        const float h2 = o2 * tanz(C2 * N2LOG2E);                        \
        const float i3 = sigz(AC0[3]), f3 = sigz(AC1[3]);                \
        const float g3 = tanz(AC2[3]), o3 = sigz(AC3[3]);                \
        C3 = __builtin_fmaf(f3, C3, i3 * g3);                            \
        const float h3 = o3 * tanz(C3 * N2LOG2E);                        \
        HV[0] = (_Float16)h0; HV[1] = (_Float16)h1;                      \
        HV[2] = (_Float16)h2; HV[3] = (_Float16)h3;                      \
    }

__global__ __launch_bounds__(NT, 2) void lstm_fused(
    const float* __restrict__ x,      // (S,3,12): s*36 + f*12 + t
    const float* __restrict__ W_ih,   // (512,3)
    const float* __restrict__ W_hh,   // (512,128)
    const float* __restrict__ b_ih,   // (512)
    const float* __restrict__ b_hh,   // (512)
    const float* __restrict__ W_lin,  // (128)
    const float* __restrict__ b_lin,  // (1)
    float* __restrict__ out)          // (S,12): s*12 + t
{
    const int tid = threadIdx.x;
    const int w   = tid >> 6;    // wave 0..3
    const int l   = tid & 63;
    const int n   = l & 15;      // chain col; for A, l&15 is row m
    const int qk  = l >> 4;      // k-quad / row-quad
    const int t0  = w;           // first j-tile owned by this wave
    const int t1  = w + 4;       // second j-tile

    const int ostart = blockIdx.x * CHUNK_L;
    const int oend   = min(ostart + CHUNK_L, S_TOTAL);
    const int sbeg   = max(0, ostart - WARMUP);
    const int nsteps = oend - sbeg;

    __shared__ __align__(16) _Float16 hfrag[2][5][64][8];   // 10240 B
    __shared__ __align__(16) float pout2[2][16][32];        // 4096 B

    // ---- A fragments: 2 tiles x 4 gates x 5 kt (fp16, scales folded) ----
    half8 A0[4][5], A1[4][5];
#pragma unroll
    for (int q = 0; q < 4; ++q) {
        const float sc = (q == 2) ? N2LOG2E : NLOG2E;
        {
            const int row = q * HID + 16 * t0 + n;
#pragma unroll
            for (int kt = 0; kt < 4; ++kt) {
                const float* src = &W_hh[row * HID + kt * 32 + qk * 8];
                half8 a;
#pragma unroll
                for (int e = 0; e < 8; ++e) a[e] = (_Float16)(src[e] * sc);
                A0[q][kt] = a;
            }
            half8 ae = {};
            if (qk == 0) {
                ae[0] = (_Float16)(W_ih[row * 3 + 0] * sc);
                ae[1] = (_Float16)(W_ih[row * 3 + 1] * sc);
                ae[2] = (_Float16)(W_ih[row * 3 + 2] * sc);
                ae[3] = (_Float16)((b_ih[row] + b_hh[row]) * sc);
            }
            A0[q][4] = ae;
        }
        {
            const int row = q * HID + 16 * t1 + n;
#pragma unroll
            for (int kt = 0; kt < 4; ++kt) {
                const float* src = &W_hh[row * HID + kt * 32 + qk * 8];
                half8 a;
#pragma unroll
                for (int e = 0; e < 8; ++e) a[e] = (_Float16)(src[e] * sc);
                A1[q][kt] = a;
            }
            half8 ae = {};
            if (qk == 0) {
                ae[0] = (_Float16)(W_ih[row * 3 + 0] * sc);
                ae[1] = (_Float16)(W_ih[row * 3 + 1] * sc);
                ae[2] = (_Float16)(W_ih[row * 3 + 2] * sc);
                ae[3] = (_Float16)((b_ih[row] + b_hh[row]) * sc);
            }
            A1[q][4] = ae;
        }
    }

    // W_lin pairs for this lane's output rows: tile0 j00..j00+3, tile1 +64
    const int j00 = 16 * t0 + 4 * qk;
    half2v wl01_0, wl23_0, wl01_1, wl23_1;
    wl01_0[0] = (_Float16)W_lin[j00];      wl01_0[1] = (_Float16)W_lin[j00 + 1];
    wl23_0[0] = (_Float16)W_lin[j00 + 2];  wl23_0[1] = (_Float16)W_lin[j00 + 3];
    wl01_1[0] = (_Float16)W_lin[j00 + 64]; wl01_1[1] = (_Float16)W_lin[j00 + 65];
    wl23_1[0] = (_Float16)W_lin[j00 + 66]; wl23_1[1] = (_Float16)W_lin[j00 + 67];
    const float blin = b_lin[0];

    // ---- zero LDS; seed bias + x(sbeg) ----
    uint4* hz = (uint4*)hfrag;                  // 640 uint4
    hz[tid]       = make_uint4(0, 0, 0, 0);
    hz[tid + 256] = make_uint4(0, 0, 0, 0);
    if (tid < 128) hz[tid + 512] = make_uint4(0, 0, 0, 0);
    __syncthreads();
    if (tid < 16) {
        hfrag[0][4][tid][3] = (_Float16)1.0f;
        hfrag[1][4][tid][3] = (_Float16)1.0f;
    }
    if (tid < T_CH) {
        hfrag[0][4][tid][0] = (_Float16)x[sbeg * 36 + tid];
        hfrag[0][4][tid][1] = (_Float16)x[sbeg * 36 + 12 + tid];
        hfrag[0][4][tid][2] = (_Float16)x[sbeg * 36 + 24 + tid];
    }

    // ---- hoisted addresses ----
    const _Float16* rb0 = &hfrag[0][0][l][0];
    const _Float16* rb1 = &hfrag[1][0][l][0];
    const int lp0 = (2 * (t0 & 1) + (qk >> 1)) * 16 + n;
    const int lp1 = (2 * (t1 & 1) + (qk >> 1)) * 16 + n;
    _Float16* wbT0_0 = &hfrag[0][t0 >> 1][lp0][4 * (qk & 1)];
    _Float16* wbT0_1 = &hfrag[1][t0 >> 1][lp0][4 * (qk & 1)];
    _Float16* wbT1_0 = &hfrag[0][t1 >> 1][lp1][4 * (qk & 1)];
    _Float16* wbT1_1 = &hfrag[1][t1 >> 1][lp1][4 * (qk & 1)];

    // pout2 swizzled slots, keyed by tile: slot(t)=(4t+qk+4n)&31
    const int ps0 = (4 * t0 + qk + 4 * n) & 31;
    const int ps1 = ps0 ^ 16;                   // (ps0+16)&31

    float c00 = 0.f, c01 = 0.f, c02 = 0.f, c03 = 0.f;
    float c10 = 0.f, c11 = 0.f, c12 = 0.f, c13 = 0.f;

    // 2-deep x pipeline in wave 0 (issued top-of-slot -> 2 slots to drain)
    float xn1a = 0.f, xn1b = 0.f, xn1c = 0.f;
    float xn2a = 0.f, xn2b = 0.f, xn2c = 0.f;
    if (w == 0 && l < T_CH) {
        const int s1 = min(sbeg + 1, S_TOTAL - 1);
        const int s2 = min(sbeg + 2, S_TOTAL - 1);
        xn1a = x[s1 * 36 + l]; xn1b = x[s1 * 36 + 12 + l]; xn1c = x[s1 * 36 + 24 + l];
        xn2a = x[s2 * 36 + l]; xn2b = x[s2 * 36 + 12 + l]; xn2c = x[s2 * 36 + 24 + l];
    }
    __syncthreads();

    auto step = [&](const int p, const int s) {
        // ---- TOP: wave 0 x pipeline ----
        if (w == 0 && l < T_CH) {
            _Float16* xd = p ? &hfrag[0][4][l][0] : &hfrag[1][4][l][0];
            half2v xp; xp[0] = (_Float16)xn1a; xp[1] = (_Float16)xn1b;
            *(half2v*)xd = xp;
            xd[2] = (_Float16)xn1c;
            xn1a = xn2a; xn1b = xn2b; xn1c = xn2c;
            const int sn = min(s + 3, S_TOTAL - 1);
            xn2a = x[sn * 36 + l];
            xn2b = x[sn * 36 + 12 + l];
            xn2c = x[sn * 36 + 24 + l];
        }
        // ---- TOP: wave 3 combines LAST step's partials -> out[s-1] ----
        if (w == 3 && l < T_CH && s > ostart) {
            const float* pr = &pout2[p ^ 1][l][0];
            RD8(pr, out[(s - 1) * T_CH + l]);
        }

        // ---- B-frag ds_reads ----
        const _Float16* rb = p ? rb1 : rb0;
        const half8 B0 = *(const half8*)(rb + 0 * 512);
        const half8 B1 = *(const half8*)(rb + 1 * 512);
        const half8 B2 = *(const half8*)(rb + 2 * 512);
        const half8 B3 = *(const half8*)(rb + 3 * 512);
        const half8 B4 = *(const half8*)(rb + 4 * 512);

        // ---- tile 0: MFMA + gates + h-store ----
        TILE_MFMA(A0, ac00, ac01, ac02, ac03);
        half4v hv0;
        TILE_GATES(ac00, ac01, ac02, ac03, c00, c01, c02, c03, hv0);
        *(half4v*)(p ? wbT0_0 : wbT0_1) = hv0;

        // ---- tile 1: MFMA + gates + h-store ----
        TILE_MFMA(A1, ac10, ac11, ac12, ac13);
        half4v hv1;
        TILE_GATES(ac10, ac11, ac12, ac13, c10, c11, c12, c13, hv1);
        *(half4v*)(p ? wbT1_0 : wbT1_1) = hv1;

        // ---- W_lin partials -> swizzled pout2 ----
        if (s >= ostart) {
            half2v h01, h23;
            h01[0] = hv0[0]; h01[1] = hv0[1];
            h23[0] = hv0[2]; h23[1] = hv0[3];
            pout2[p][n][ps0] = fdot2(h23, wl23_0, fdot2(h01, wl01_0, 0.0f));
            h01[0] = hv1[0]; h01[1] = hv1[1];
            h23[0] = hv1[2]; h23[1] = hv1[3];
            pout2[p][n][ps1] = fdot2(h23, wl23_1, fdot2(h01, wl01_1, 0.0f));
        }
        __syncthreads();
    };

    int ss = 0;
    for (; ss + 2 <= nsteps; ss += 2) {
        step(0, sbeg + ss);
        step(1, sbeg + ss + 1);
    }
    if (ss < nsteps) step(0, sbeg + ss);   // tail (ss even here)

    // ---- epilogue: out[oend-1] from the last step's partials ----
    if (w == 3 && l < T_CH) {
        const float* pr = &pout2[(nsteps - 1) & 1][l][0];
        RD8(pr, out[(oend - 1) * T_CH + l]);
    }
}

extern "C" void kernel_launch(void* const* d_in, const int* in_sizes, int n_in,
                              void* d_out, int out_size, void* d_ws, size_t ws_size,
                              hipStream_t stream) {
    const float* x     = (const float*)d_in[0];
    const float* W_ih  = (const float*)d_in[1];
    const float* W_hh  = (const float*)d_in[2];
    const float* b_ih  = (const float*)d_in[3];
    const float* b_hh  = (const float*)d_in[4];
    const float* W_lin = (const float*)d_in[5];
    const float* b_lin = (const float*)d_in[6];
    float* out = (float*)d_out;

    hipLaunchKernelGGL(lstm_fused, dim3(NBLK), dim3(NT), 0, stream,
                       x, W_ih, W_hh, b_ih, b_hh, W_lin, b_lin, out);
}